// Round 1
// baseline (763.654 us; speedup 1.0000x reference)
//
#include <hip/hip_runtime.h>
#include <stdint.h>

#define HW 512
#define IMG (HW*HW)
#define BATCH 16
#define CNUM_ 6
#define LNUM_ 3

// ws float-index layout:
// [0..15]  umin (uint)   [16..31] umax (uint)
// [32..47] mn  [48..63] scale  [64..79] inv_scale
// [128 + (b*6+i)*WREC_F ...] weight records
#define WREC_F 321
#define OFF_WEFF 0      // 3*25 composed 5x5
#define OFF_BEFF 75     // 3
#define OFF_PP   78     // 3*4 sigmoid'd bezier params
#define OFF_W1   90     // 3*36 raw (for border-exact path)
#define OFF_B1   198    // 3*4
#define OFF_W2   210    // 3*36
#define OFF_B2   318    // 3

__device__ inline unsigned enc_ord(float f){
    unsigned u = __float_as_uint(f);
    return u ^ (unsigned)(((int)u >> 31) | 0x80000000);
}
__device__ inline float dec_ord(unsigned u){
    return (u & 0x80000000u) ? __uint_as_float(u ^ 0x80000000u) : __uint_as_float(~u);
}

__global__ void k_init(unsigned* ws){
    int t = threadIdx.x;
    if (t < 16){ ws[t] = 0xFFFFFFFFu; ws[16 + t] = 0u; }
}

__global__ __launch_bounds__(256) void k_minmax(const float4* __restrict__ x, unsigned* __restrict__ ws){
    int b = blockIdx.x >> 4, chunk = blockIdx.x & 15;
    int base4 = b * (IMG/4) + chunk * 4096;
    float vmin = 1e30f, vmax = -1e30f;
#pragma unroll
    for (int k = 0; k < 16; k++){
        float4 v = x[base4 + k*256 + threadIdx.x];
        vmin = fminf(vmin, fminf(fminf(v.x, v.y), fminf(v.z, v.w)));
        vmax = fmaxf(vmax, fmaxf(fmaxf(v.x, v.y), fmaxf(v.z, v.w)));
    }
#pragma unroll
    for (int off = 32; off > 0; off >>= 1){
        vmin = fminf(vmin, __shfl_down(vmin, off));
        vmax = fmaxf(vmax, __shfl_down(vmax, off));
    }
    if ((threadIdx.x & 63) == 0){
        atomicMin(&ws[b], enc_ord(vmin));
        atomicMax(&ws[16 + b], enc_ord(vmax));
    }
}

__global__ void k_prep(const int* __restrict__ index, const float* __restrict__ param,
                       const float* __restrict__ w1, const float* __restrict__ b1,
                       const float* __restrict__ w2, const float* __restrict__ b2,
                       unsigned* __restrict__ wsu, float* __restrict__ wsf){
    int t = threadIdx.x;
    if (t < 16){
        float mn = dec_ord(wsu[t]), mx = dec_ord(wsu[16 + t]);
        float sc = mx - mn + 1e-8f;
        wsf[32 + t] = mn; wsf[48 + t] = sc; wsf[64 + t] = 1.0f / sc;
    }
    if (t < BATCH * CNUM_ * LNUM_){
        int b = t / 18, r = t % 18, i = r / 3, l = r % 3;
        int idx = index[b];
        int base4 = ((idx * CNUM_ + i) * 4 + 0) * LNUM_ + l;  // (idx, i, aug=0, l)
        float* rec = wsf + 128 + (b * CNUM_ + i) * WREC_F;
#pragma unroll
        for (int k = 0; k < 4; k++){
            float v = param[base4 * 7 + k];
            rec[OFF_PP + l*4 + k] = 1.0f / (1.0f + __expf(-v));
        }
        float w1v[36], w2v[36], b1v[4];
#pragma unroll
        for (int k = 0; k < 36; k++){ w1v[k] = w1[base4*36 + k]; w2v[k] = w2[base4*36 + k]; }
#pragma unroll
        for (int k = 0; k < 4; k++) b1v[k] = b1[base4*4 + k];
        float b2v = b2[base4];
        float we[25];
#pragma unroll
        for (int k = 0; k < 25; k++) we[k] = 0.f;
        float be = b2v;
#pragma unroll
        for (int c = 0; c < 4; c++){
            float s2 = 0.f;
#pragma unroll
            for (int q = 0; q < 9; q++) s2 += w2v[c*9 + q];
            be += b1v[c] * s2;
#pragma unroll
            for (int ky2 = 0; ky2 < 3; ky2++)
#pragma unroll
            for (int kx2 = 0; kx2 < 3; kx2++){
                float wv2 = w2v[c*9 + ky2*3 + kx2];
#pragma unroll
                for (int ky1 = 0; ky1 < 3; ky1++)
#pragma unroll
                for (int kx1 = 0; kx1 < 3; kx1++)
                    we[(ky2 + ky1)*5 + (kx2 + kx1)] += wv2 * w1v[c*9 + ky1*3 + kx1];
            }
        }
#pragma unroll
        for (int k = 0; k < 25; k++) rec[OFF_WEFF + l*25 + k] = we[k];
        rec[OFF_BEFF + l] = be;
#pragma unroll
        for (int k = 0; k < 36; k++){ rec[OFF_W1 + l*36 + k] = w1v[k]; rec[OFF_W2 + l*36 + k] = w2v[k]; }
#pragma unroll
        for (int k = 0; k < 4; k++) rec[OFF_B1 + l*4 + k] = b1v[k];
        rec[OFF_B2 + l] = b2v;
    }
}

// One class pass: for pixels with lbl==cls, compute 3-layer mix/bezier from state
// s_i(q) = (lbl(q)<cls ? final(q) : x(q)) normalized; write denormalized result.
__global__ __launch_bounds__(256) void k_class(int cls,
        const float* __restrict__ x, const int* __restrict__ lbl,
        float* __restrict__ out, const float* __restrict__ wsf){
    __shared__ float s[36][37];
    __shared__ float wts[WREC_F];
    __shared__ int list[1024];
    __shared__ int cnt;
    int b = blockIdx.z;
    int X0 = blockIdx.x * 32 - 2, Y0 = blockIdx.y * 32 - 2;
    float mn = wsf[32 + b], sc = wsf[48 + b], inv = wsf[64 + b];
    const float* rec = wsf + 128 + (b * CNUM_ + cls) * WREC_F;
    int tid = threadIdx.x;
    const int sbase = b * IMG;

    for (int k = tid; k < WREC_F; k += 256) wts[k] = rec[k];
    if (tid == 0) cnt = 0;
    // stage 36x36 selected+normalized state tile (zero outside image)
    for (int k = tid; k < 36*36; k += 256){
        int ly = k / 36, lx = k % 36;
        int gy = Y0 + ly, gx = X0 + lx;
        float v = 0.f;
        if (gy >= 0 && gy < HW && gx >= 0 && gx < HW){
            int off = sbase + gy*HW + gx;
            int lq = lbl[off];
            float raw = (lq < cls) ? out[off] : x[off];
            v = (raw - mn) * inv;
        }
        s[ly][lx] = v;
    }
    __syncthreads();
    // compact class-cls pixels of the 32x32 tile into a list
    int px = tid & 31, tq = tid >> 5;
    for (int r = 0; r < 4; r++){
        int py = tq * 4 + r;
        int gy = Y0 + 2 + py, gx = X0 + 2 + px;
        int myl = lbl[sbase + gy*HW + gx];
        bool m = (myl == cls);
        unsigned long long mask = __ballot(m);
        int lane = tid & 63;
        int wbase = 0;
        if (lane == 0) wbase = atomicAdd(&cnt, __popcll(mask));
        wbase = __shfl(wbase, 0);
        if (m){
            int pos = wbase + __popcll(mask & ((1ull << lane) - 1ull));
            list[pos] = py*32 + px;
        }
    }
    __syncthreads();
    int n = cnt;
    for (int j = tid; j < n; j += 256){
        int pix = list[j];
        int py = pix >> 5, lpx = pix & 31;
        int ly = py + 2, lx = lpx + 2;
        int gy = Y0 + 2 + py, gx = X0 + 2 + lpx;
        float nb[5][5];
#pragma unroll
        for (int a = 0; a < 5; a++)
#pragma unroll
        for (int bb = 0; bb < 5; bb++) nb[a][bb] = s[ly - 2 + a][lx - 2 + bb];
        float c = nb[2][2];
        bool ring = (gy == 0) | (gy == HW-1) | (gx == 0) | (gx == HW-1);
#pragma unroll
        for (int l = 0; l < LNUM_; l++){
            float z;
            if (!ring){
                z = wts[OFF_BEFF + l];
#pragma unroll
                for (int e = 0; e < 25; e++) z += wts[OFF_WEFF + l*25 + e] * nb[e/5][e%5];
            } else {
                // exact nested 2-conv with zero-padded intermediate
                z = wts[OFF_B2 + l];
#pragma unroll
                for (int d = 0; d < 9; d++){
                    int dy = d/3 - 1, dx = d%3 - 1;
                    int qy = gy + dy, qx = gx + dx;
                    if (qy >= 0 && qy < HW && qx >= 0 && qx < HW){
#pragma unroll
                        for (int ch = 0; ch < 4; ch++){
                            float y = wts[OFF_B1 + l*4 + ch];
#pragma unroll
                            for (int d2 = 0; d2 < 9; d2++){
                                int dy2 = d2/3 - 1, dx2 = d2%3 - 1;
                                y += wts[OFF_W1 + l*36 + ch*9 + d2] * nb[2 + dy + dy2][2 + dx + dx2];
                            }
                            z += wts[OFF_W2 + l*36 + ch*9 + d] * y;
                        }
                    }
                }
            }
            float mix = 1.0f / (1.0f + __expf(-z));
            float p1  = wts[OFF_PP + l*4 + 0], p2  = wts[OFF_PP + l*4 + 1];
            float p1v = wts[OFF_PP + l*4 + 2], p2v = wts[OFF_PP + l*4 + 3];
            float om = 1.0f - c;
            float om2 = om * om, c2 = c * c;
            float ct = 3.f*om2*c*p1 + 3.f*om*c2*p2 + c2*c;
            float cv = om2*om + 3.f*om2*c*p1v + 3.f*om*c2*p2v;
            c = ct * mix + cv * (1.f - mix);
            c = fminf(fmaxf(c, 0.f), 1.f);
        }
        out[sbase + gy*HW + gx] = c * sc + mn;
    }
}

extern "C" void kernel_launch(void* const* d_in, const int* in_sizes, int n_in,
                              void* d_out, int out_size, void* d_ws, size_t ws_size,
                              hipStream_t stream){
    const float* x     = (const float*)d_in[0];
    const int*   lbl   = (const int*)  d_in[1];
    const int*   index = (const int*)  d_in[2];
    const float* param = (const float*)d_in[3];
    const float* w1    = (const float*)d_in[4];
    const float* b1    = (const float*)d_in[5];
    const float* w2    = (const float*)d_in[6];
    const float* b2    = (const float*)d_in[7];
    float* out = (float*)d_out;
    unsigned* wsu = (unsigned*)d_ws;
    float* wsf = (float*)d_ws;

    k_init<<<1, 32, 0, stream>>>(wsu);
    k_minmax<<<256, 256, 0, stream>>>((const float4*)x, wsu);
    k_prep<<<1, 320, 0, stream>>>(index, param, w1, b1, w2, b2, wsu, wsf);
    dim3 g(16, 16, 16);
    for (int i = 0; i < CNUM_; i++)
        k_class<<<g, 256, 0, stream>>>(i, x, lbl, out, wsf);
}

// Round 2
// 547.115 us; speedup vs baseline: 1.3958x; 1.3958x over previous
//
#include <hip/hip_runtime.h>
#include <stdint.h>

#define HW 512
#define IMG (HW*HW)
#define BATCH 16
#define CNUM_ 6
#define LNUM_ 3
#define TILE 32
#define HALO 12
#define ST (TILE + 2*HALO)   // 56
#define STP (ST + 1)         // 57 (pad)

// ws float-index layout:
// [0..15]  umin (uint)   [16..31] umax (uint)
// [32..47] mn  [48..63] scale  [64..79] inv_scale
// [128 + (b*6+i)*WREC_F ...] weight records
#define WREC_F 321
#define OFF_WEFF 0      // 3*25 composed 5x5
#define OFF_BEFF 75     // 3
#define OFF_PP   78     // 3*4 sigmoid'd bezier params
#define OFF_W1   90     // 3*36 raw (border-exact path)
#define OFF_B1   198    // 3*4
#define OFF_W2   210    // 3*36
#define OFF_B2   318    // 3

__device__ inline unsigned enc_ord(float f){
    unsigned u = __float_as_uint(f);
    return u ^ (unsigned)(((int)u >> 31) | 0x80000000);
}
__device__ inline float dec_ord(unsigned u){
    return (u & 0x80000000u) ? __uint_as_float(u ^ 0x80000000u) : __uint_as_float(~u);
}

__global__ void k_init(unsigned* ws){
    int t = threadIdx.x;
    if (t < 16){ ws[t] = 0xFFFFFFFFu; ws[16 + t] = 0u; }
}

__global__ __launch_bounds__(256) void k_minmax(const float4* __restrict__ x, unsigned* __restrict__ ws){
    int b = blockIdx.x >> 4, chunk = blockIdx.x & 15;
    int base4 = b * (IMG/4) + chunk * 4096;
    float vmin = 1e30f, vmax = -1e30f;
#pragma unroll
    for (int k = 0; k < 16; k++){
        float4 v = x[base4 + k*256 + threadIdx.x];
        vmin = fminf(vmin, fminf(fminf(v.x, v.y), fminf(v.z, v.w)));
        vmax = fmaxf(vmax, fmaxf(fmaxf(v.x, v.y), fmaxf(v.z, v.w)));
    }
#pragma unroll
    for (int off = 32; off > 0; off >>= 1){
        vmin = fminf(vmin, __shfl_down(vmin, off));
        vmax = fmaxf(vmax, __shfl_down(vmax, off));
    }
    if ((threadIdx.x & 63) == 0){
        atomicMin(&ws[b], enc_ord(vmin));
        atomicMax(&ws[16 + b], enc_ord(vmax));
    }
}

__global__ void k_prep(const int* __restrict__ index, const float* __restrict__ param,
                       const float* __restrict__ w1, const float* __restrict__ b1,
                       const float* __restrict__ w2, const float* __restrict__ b2,
                       unsigned* __restrict__ wsu, float* __restrict__ wsf){
    int t = threadIdx.x;
    if (t < 16){
        float mn = dec_ord(wsu[t]), mx = dec_ord(wsu[16 + t]);
        float sc = mx - mn + 1e-8f;
        wsf[32 + t] = mn; wsf[48 + t] = sc; wsf[64 + t] = 1.0f / sc;
    }
    if (t < BATCH * CNUM_ * LNUM_){
        int b = t / 18, r = t % 18, i = r / 3, l = r % 3;
        int idx = index[b];
        int base4 = ((idx * CNUM_ + i) * 4 + 0) * LNUM_ + l;  // (idx, i, aug=0, l)
        float* rec = wsf + 128 + (b * CNUM_ + i) * WREC_F;
#pragma unroll
        for (int k = 0; k < 4; k++){
            float v = param[base4 * 7 + k];
            rec[OFF_PP + l*4 + k] = 1.0f / (1.0f + __expf(-v));
        }
        float w1v[36], w2v[36], b1v[4];
#pragma unroll
        for (int k = 0; k < 36; k++){ w1v[k] = w1[base4*36 + k]; w2v[k] = w2[base4*36 + k]; }
#pragma unroll
        for (int k = 0; k < 4; k++) b1v[k] = b1[base4*4 + k];
        float b2v = b2[base4];
        float we[25];
#pragma unroll
        for (int k = 0; k < 25; k++) we[k] = 0.f;
        float be = b2v;
#pragma unroll
        for (int c = 0; c < 4; c++){
            float s2 = 0.f;
#pragma unroll
            for (int q = 0; q < 9; q++) s2 += w2v[c*9 + q];
            be += b1v[c] * s2;
#pragma unroll
            for (int ky2 = 0; ky2 < 3; ky2++)
#pragma unroll
            for (int kx2 = 0; kx2 < 3; kx2++){
                float wv2 = w2v[c*9 + ky2*3 + kx2];
#pragma unroll
                for (int ky1 = 0; ky1 < 3; ky1++)
#pragma unroll
                for (int kx1 = 0; kx1 < 3; kx1++)
                    we[(ky2 + ky1)*5 + (kx2 + kx1)] += wv2 * w1v[c*9 + ky1*3 + kx1];
            }
        }
#pragma unroll
        for (int k = 0; k < 25; k++) rec[OFF_WEFF + l*25 + k] = we[k];
        rec[OFF_BEFF + l] = be;
#pragma unroll
        for (int k = 0; k < 36; k++){ rec[OFF_W1 + l*36 + k] = w1v[k]; rec[OFF_W2 + l*36 + k] = w2v[k]; }
#pragma unroll
        for (int k = 0; k < 4; k++) rec[OFF_B1 + l*4 + k] = b1v[k];
        rec[OFF_B2 + l] = b2v;
    }
}

// Per-pixel 3-layer transform. s = state tile, w = this class's weight record.
// nb is the 5x5 neighborhood (zero outside image, matching SAME padding on xn).
__device__ inline float process_pixel(const float (*s)[STP], const float* __restrict__ w,
                                      int ly, int lx, int gy, int gx){
    float nb[5][5];
#pragma unroll
    for (int a = 0; a < 5; a++)
#pragma unroll
    for (int bb = 0; bb < 5; bb++) nb[a][bb] = s[ly - 2 + a][lx - 2 + bb];
    float c = nb[2][2];
    bool ring = (gy == 0) | (gy == HW-1) | (gx == 0) | (gx == HW-1);
#pragma unroll
    for (int l = 0; l < LNUM_; l++){
        float z;
        if (!ring){
            z = w[OFF_BEFF + l];
#pragma unroll
            for (int e = 0; e < 25; e++) z += w[OFF_WEFF + l*25 + e] * nb[e/5][e%5];
        } else {
            // exact nested 2-conv with zero-padded intermediate (image border only)
            z = w[OFF_B2 + l];
            for (int d = 0; d < 9; d++){
                int dy = d/3 - 1, dx = d%3 - 1;
                int qy = gy + dy, qx = gx + dx;
                if (qy >= 0 && qy < HW && qx >= 0 && qx < HW){
                    for (int ch = 0; ch < 4; ch++){
                        float y = w[OFF_B1 + l*4 + ch];
                        for (int d2 = 0; d2 < 9; d2++){
                            int dy2 = d2/3 - 1, dx2 = d2%3 - 1;
                            y += w[OFF_W1 + l*36 + ch*9 + d2] * nb[2 + dy + dy2][2 + dx + dx2];
                        }
                        z += w[OFF_W2 + l*36 + ch*9 + d] * y;
                    }
                }
            }
        }
        float mix = 1.0f / (1.0f + __expf(-z));
        float p1  = w[OFF_PP + l*4 + 0], p2  = w[OFF_PP + l*4 + 1];
        float p1v = w[OFF_PP + l*4 + 2], p2v = w[OFF_PP + l*4 + 3];
        float om = 1.0f - c;
        float om2 = om * om, c2 = c * c;
        float ct = 3.f*om2*c*p1 + 3.f*om*c2*p2 + c2*c;
        float cv = om2*om + 3.f*om2*c*p1v + 3.f*om*c2*p2v;
        c = ct * mix + cv * (1.f - mix);
        c = fminf(fmaxf(c, 0.f), 1.f);
    }
    return c;
}

// Fused: stage 56x56 (12-halo) normalized tile + labels once, run all 6 class
// passes in LDS (region shrinks 2/side/pass), write the 32x32 core once.
__global__ __launch_bounds__(256) void k_fused(
        const float* __restrict__ x, const int* __restrict__ lbl,
        float* __restrict__ out, const float* __restrict__ wsf){
    __shared__ float s[ST][STP];
    __shared__ short slbl[ST][STP];
    __shared__ float wts[CNUM_ * WREC_F];
    __shared__ unsigned short list[52*52];
    __shared__ int cnt;
    int b = blockIdx.z;
    int X0 = blockIdx.x * TILE - HALO, Y0 = blockIdx.y * TILE - HALO;
    float mn = wsf[32 + b], sc = wsf[48 + b], inv = wsf[64 + b];
    int tid = threadIdx.x;
    const int sbase = b * IMG;

    for (int k = tid; k < CNUM_ * WREC_F; k += 256)
        wts[k] = wsf[128 + (b * CNUM_) * WREC_F + k];

    // stage normalized state + labels (zero / -1 outside image)
    for (int k = tid; k < ST*ST; k += 256){
        int ly = k / ST, lx = k % ST;
        int gy = Y0 + ly, gx = X0 + lx;
        float v = 0.f; short l8 = -1;
        if (gy >= 0 && gy < HW && gx >= 0 && gx < HW){
            int off = sbase + gy*HW + gx;
            v = (x[off] - mn) * inv;
            l8 = (short)lbl[off];
        }
        s[ly][lx] = v;
        slbl[ly][lx] = l8;
    }

    float upd[11];

#pragma unroll
    for (int cls = 0; cls < CNUM_; cls++){
        const int lo = 2 + 2*cls;        // region margin within staged tile
        const int W  = ST - 2*lo;        // 52,48,44,40,36,32
        const float* w = wts + cls * WREC_F;
        __syncthreads();                 // staging done / prev pass writes done
        if (tid == 0) cnt = 0;
        __syncthreads();
        // compact this pass's pixels
        for (int j = tid; j < W*W; j += 256){
            int ly = lo + j / W, lx = lo + j % W;
            bool m = (slbl[ly][lx] == cls);
            unsigned long long mask = __ballot(m);
            int lane = tid & 63;
            int wbase = 0;
            if (lane == 0) wbase = atomicAdd(&cnt, __popcll(mask));
            wbase = __shfl(wbase, 0);
            if (m){
                int pos = wbase + __popcll(mask & ((1ull << lane) - 1ull));
                list[pos] = (unsigned short)((ly << 8) | lx);
            }
        }
        __syncthreads();
        int n = cnt;
        // compute updates into registers (pass-start state semantics)
        for (int j = tid, k = 0; j < n; j += 256, k++){
            int e = list[j];
            int ly = e >> 8, lx = e & 255;
            upd[k] = process_pixel(s, w, ly, lx, Y0 + ly, X0 + lx);
        }
        __syncthreads();
        // write back
        for (int j = tid, k = 0; j < n; j += 256, k++){
            int e = list[j];
            s[e >> 8][e & 255] = upd[k];
        }
    }
    __syncthreads();
    // store core, denormalized
    for (int j = tid; j < TILE*TILE; j += 256){
        int py = j >> 5, px = j & 31;
        int gy = Y0 + HALO + py, gx = X0 + HALO + px;
        out[sbase + gy*HW + gx] = s[HALO + py][HALO + px] * sc + mn;
    }
}

extern "C" void kernel_launch(void* const* d_in, const int* in_sizes, int n_in,
                              void* d_out, int out_size, void* d_ws, size_t ws_size,
                              hipStream_t stream){
    const float* x     = (const float*)d_in[0];
    const int*   lbl   = (const int*)  d_in[1];
    const int*   index = (const int*)  d_in[2];
    const float* param = (const float*)d_in[3];
    const float* w1    = (const float*)d_in[4];
    const float* b1    = (const float*)d_in[5];
    const float* w2    = (const float*)d_in[6];
    const float* b2    = (const float*)d_in[7];
    float* out = (float*)d_out;
    unsigned* wsu = (unsigned*)d_ws;
    float* wsf = (float*)d_ws;

    k_init<<<1, 32, 0, stream>>>(wsu);
    k_minmax<<<256, 256, 0, stream>>>((const float4*)x, wsu);
    k_prep<<<1, 320, 0, stream>>>(index, param, w1, b1, w2, b2, wsu, wsf);
    dim3 g(16, 16, 16);
    k_fused<<<g, 256, 0, stream>>>(x, lbl, out, wsf);
}